// Round 7
// baseline (802.754 us; speedup 1.0000x reference)
//
#include <hip/hip_runtime.h>
#include <stdint.h>

// ---- problem constants ----
#define NB   32        // batch
#define NCH  128       // num atoms
#define IMG  64
#define IMG2 4096      // 64*64
#define OH   57        // 64-8+1
#define OHW  3249      // 57*57
#define CHW  415872    // 128*3249 (per-sample code size)
#define KTOP 256       // sparsity K
#define NATT 17        // alphas 2^0 .. 2^-16 (while count<=15 semantics)
#define NS   32        // candidate counter slices per sample (atomic spread)
#define SCAP 512       // capacity per slice
#define NCAP 1536      // collected (non-support) cap in k_suppg
#define NBUCK 8192     // |g| histogram buckets (top 13 bits: sign+exp8+mant4)
#define HSHIFT 18      // bits >> 18 -> bucket
#define TGT  512       // keep at least top-512 of |g| (superset of top-256 non-support)
#define RSTRIDE 72     // recon LDS row stride (2-way banks, free)
#define NZB  257       // zero-blocks fused into k_resid (256 hist + 1 cand_cnt)

typedef unsigned long long ull;

// ---------------- init: support count = 0 ----------------
__global__ void k_init(int* support_cnt) {
    if (threadIdx.x < NB) support_cnt[threadIdx.x] = 0;
}

// ---------------- R = Y - D*X (sparse scatter) + fused zeroing ----------------
__global__ __launch_bounds__(256) void k_resid(
    const float* __restrict__ Y, const float* __restrict__ W,
    const int* __restrict__ support_cnt, const uint32_t* __restrict__ support_idx,
    const float* __restrict__ support_val, float* __restrict__ Rg, double* __restrict__ l2part,
    uint32_t* __restrict__ hist, int* __restrict__ cand_cnt)
{
    int bx = blockIdx.x, tid = threadIdx.x;
    if (bx >= NB) {
        int zb = bx - NB;
        if (zb < 256) {
            ((uint4*)hist)[zb * 256 + tid] = make_uint4(0u, 0u, 0u, 0u);
        } else {
            ((uint4*)cand_cnt)[tid] = make_uint4(0u, 0u, 0u, 0u);
        }
        return;
    }
    int b = bx;
    __shared__ float Rs[IMG2];
    const float4* Y4 = (const float4*)(Y + b * IMG2);
    float4* R4 = (float4*)Rs;
    for (int i = tid; i < IMG2 / 4; i += 256) R4[i] = Y4[i];
    __syncthreads();
    int n = support_cnt[b];
    for (int task = tid; task < n * 64; task += 256) {
        int i = task >> 6, tap = task & 63, p = tap >> 3, q = tap & 7;
        uint32_t idx = support_idx[b * KTOP + i];
        float val = support_val[b * KTOP + i];
        int c = idx / OHW, rem = idx % OHW, s = rem / OH, t = rem % OH;
        float w = W[c * 64 + p * 8 + q];
        atomicAdd(&Rs[(s + p) * IMG + (t + q)], -val * w);
    }
    __syncthreads();
    double acc = 0.0;
    for (int i = tid; i < IMG2; i += 256) {
        float v = Rs[i];
        Rg[b * IMG2 + i] = v;
        acc += (double)v * (double)v;
    }
    __shared__ double red[256];
    red[tid] = acc; __syncthreads();
    for (int s2 = 128; s2 > 0; s2 >>= 1) { if (tid < s2) red[tid] += red[tid + s2]; __syncthreads(); }
    if (tid == 0) l2part[b] = red[0];
}

// ---------------- g = D^T * R (dense) + fine |g| histogram ----------------
__global__ __launch_bounds__(256) void k_conv(
    const float* __restrict__ Rg, const float* __restrict__ W,
    float* __restrict__ g_out, uint32_t* __restrict__ hist)
{
    int b = blockIdx.x, cg0 = blockIdx.y, tid = threadIdx.x;
    __shared__ float Rs[71 * 72];
    __shared__ uint32_t hl[NBUCK];
    for (int i = tid; i < 71 * 72; i += 256) Rs[i] = 0.f;
    for (int i = tid; i < NBUCK; i += 256) hl[i] = 0u;
    __syncthreads();
    const float4* R4 = (const float4*)(Rg + b * IMG2);
    for (int i = tid; i < 1024; i += 256) {
        int row = i >> 4, col4 = (i & 15) * 4;
        *(float4*)&Rs[row * 72 + col4] = R4[i];
    }
    __syncthreads();
    int csub = tid >> 7;
    int tile = tid & 127;
    bool active = tile < 120;
    int tr = active ? tile / 15 : 0;
    int tc = active ? tile % 15 : 0;
    int s0 = tr * 8, t0 = tc * 4;

    for (int sub = 0; sub < 4; ++sub) {
        int c = cg0 * 8 + sub * 2 + csub;
        int c_s = __builtin_amdgcn_readfirstlane(c);
        const float* Wc = W + c_s * 64;

        float acc[8][4];
#pragma unroll
        for (int r = 0; r < 8; ++r)
#pragma unroll
            for (int cc = 0; cc < 4; ++cc) acc[r][cc] = 0.f;

#pragma unroll
        for (int rho = 0; rho < 15; ++rho) {
            float rb[12];
            const float* rp = &Rs[(s0 + rho) * 72 + t0];
            *(float4*)&rb[0] = *(const float4*)rp;
            *(float4*)&rb[4] = *(const float4*)(rp + 4);
            *(float4*)&rb[8] = *(const float4*)(rp + 8);
#pragma unroll
            for (int r = 0; r < 8; ++r) {
                const int p = rho - r;
                if (p >= 0 && p < 8) {
#pragma unroll
                    for (int q = 0; q < 8; ++q) {
                        float wv = Wc[q * 8 + p];
#pragma unroll
                        for (int cc = 0; cc < 4; ++cc)
                            acc[r][cc] = fmaf(rb[cc + q], wv, acc[r][cc]);
                    }
                }
            }
        }
        if (active) {
            float* go = g_out + (size_t)(b * NCH + c) * OHW;
#pragma unroll
            for (int r = 0; r < 8; ++r) {
                int s = s0 + r;
                if (s < OH) {
#pragma unroll
                    for (int cc = 0; cc < 4; ++cc) {
                        int t = t0 + cc;
                        if (t < OH) {
                            float v = acc[r][cc];
                            go[s * OH + t] = v;
                            uint32_t bits = __float_as_uint(v) & 0x7fffffffu;
                            atomicAdd(&hl[bits >> HSHIFT], 1u);
                        }
                    }
                }
            }
        }
    }
    __syncthreads();
    for (int i = tid; i < NBUCK; i += 256) {
        uint32_t v = hl[i];
        if (v) atomicAdd(&hist[b * NBUCK + i], v);
    }
}

// ---------------- per-sample bucket threshold (parallel suffix scan) ----------------
__global__ __launch_bounds__(256) void k_thresh(const uint32_t* __restrict__ hist,
                                                uint32_t* __restrict__ thr) {
    int b = blockIdx.x, tid = threadIdx.x;
    uint32_t h[32];
    uint32_t s = 0;
    const uint32_t* hb = hist + b * NBUCK + tid * 32;
#pragma unroll
    for (int k = 0; k < 32; ++k) { h[k] = hb[k]; s += h[k]; }
    __shared__ uint32_t buf[2][256];
    int cur = 0;
    buf[0][tid] = s;
    __syncthreads();
    for (int d = 1; d < 256; d <<= 1) {
        uint32_t v = buf[cur][tid];
        if (tid + d < 256) v += buf[cur][tid + d];
        buf[cur ^ 1][tid] = v;
        cur ^= 1;
        __syncthreads();
    }
    uint32_t sufme = buf[cur][tid];
    uint32_t base  = (tid < 255) ? buf[cur][tid + 1] : 0u;
    if (tid == 0 && buf[cur][0] < TGT) thr[b] = 0u;
    if (base < TGT && sufme >= TGT) {
        uint32_t acc = base; int bk = 0;
#pragma unroll
        for (int k = 31; k >= 0; --k) {
            acc += h[k];
            if (acc >= TGT) { bk = tid * 32 + k; break; }
        }
        thr[b] = (uint32_t)bk << HSHIFT;
    }
}

// ---------------- collect candidates: |g| above bucket threshold ----------------
__global__ __launch_bounds__(256) void k_collect(
    const float* __restrict__ g, const uint32_t* __restrict__ thr,
    int* __restrict__ cand_cnt, uint32_t* __restrict__ cand_idx, float* __restrict__ cand_g)
{
    int b = blockIdx.y;
    int i4 = blockIdx.x * 256 + threadIdx.x;
    if (i4 >= CHW / 4) return;
    int slice = blockIdx.x & (NS - 1);
    uint32_t tb = thr[b];
    float4 v4 = ((const float4*)(g + (size_t)b * CHW))[i4];
    float vv[4] = { v4.x, v4.y, v4.z, v4.w };
#pragma unroll
    for (int k = 0; k < 4; ++k) {
        uint32_t bits = __float_as_uint(vv[k]) & 0x7fffffffu;
        if (bits >= tb) {
            int pos = atomicAdd(&cand_cnt[b * NS + slice], 1);
            if (pos < SCAP) {
                cand_idx[(b * NS + slice) * SCAP + pos] = (uint32_t)(i4 * 4 + k);
                cand_g[(b * NS + slice) * SCAP + pos] = vv[k];
            }
        }
    }
}

// ---------------- build per-sample pools ----------------
// Outputs: top-256 NON-SUPPORT by (|g| desc, idx asc) with g + packed coords,
// and support g + packed coords. alpha-invariant (alpha = 2^-a exact scaling).
__global__ __launch_bounds__(256) void k_suppg(
    const float* __restrict__ g,
    const int* __restrict__ support_cnt, const uint32_t* __restrict__ support_idx,
    const float* __restrict__ support_val,
    const int* __restrict__ cand_cnt, const uint32_t* __restrict__ cand_idx,
    const float* __restrict__ cand_g,
    uint32_t* __restrict__ ns_idx, float* __restrict__ ns_g, uint32_t* __restrict__ ns_pk,
    float* __restrict__ sup_g, uint32_t* __restrict__ sup_pk)
{
    int b = blockIdx.x, tid = threadIdx.x, lane = tid & 63;
    __shared__ uint32_t sidx[KTOP];
    __shared__ float sval[KTOP];
    __shared__ int cnts[NS];
    __shared__ ull ck[NCAP];
    __shared__ float cg_l[NCAP];
    __shared__ int nns_sh;
    int n = support_cnt[b];
    if (tid < NS) cnts[tid] = min(cand_cnt[b * NS + tid], SCAP);
    if (tid == 0) nns_sh = 0;
    if (tid < n) { sidx[tid] = support_idx[b * KTOP + tid]; sval[tid] = support_val[b * KTOP + tid]; }
    __syncthreads();
    (void)sval;
    // support g + packed coords
    if (tid < n) {
        uint32_t idx = sidx[tid];
        float gv = g[(size_t)b * CHW + idx];
        sup_g[b * KTOP + tid] = gv;
        int c = idx / OHW, r = idx % OHW, s = r / OH, t = r % OH;
        sup_pk[b * KTOP + tid] = (uint32_t)((c << 12) | (s << 6) | t);
    } else {
        sup_g[b * KTOP + tid] = 0.f;
        sup_pk[b * KTOP + tid] = 0u;
    }
    // compact collected slices into LDS, filtering out support members
    for (int t0 = tid; t0 < NS * SCAP; t0 += 256) {
        int s = t0 >> 9, j = t0 & (SCAP - 1);
        bool keep = false; uint32_t idx = 0; float gv = 0.f;
        if (j < cnts[s]) {
            idx = cand_idx[(b * NS + s) * SCAP + j];
            gv = cand_g[(b * NS + s) * SCAP + j];
            int lo = 0, hi = n - 1; bool found = false;
            while (lo <= hi) {
                int mid = (lo + hi) >> 1;
                uint32_t m = sidx[mid];
                if (m == idx) { found = true; break; }
                if (m < idx) lo = mid + 1; else hi = mid - 1;
            }
            keep = !found;
        }
        ull mk = __ballot(keep);
        if (mk) {
            int basep = 0;
            if (lane == 0) basep = atomicAdd(&nns_sh, (int)__popcll(mk));
            basep = __shfl(basep, 0, 64);
            if (keep) {
                int p = basep + (int)__popcll(mk & ((1ull << lane) - 1ull));
                if (p < NCAP) {
                    ck[p] = ((ull)(__float_as_uint(gv) & 0x7fffffffu) << 32) | (ull)(uint32_t)(~idx);
                    cg_l[p] = gv;
                }
            }
        }
    }
    __syncthreads();
    int nns = min(nns_sh, NCAP);
    // exact rank among collected non-support (composite desc); rank<256 -> sorted output
    ull myk[6]; int myr[6];
#pragma unroll
    for (int q = 0; q < 6; ++q) { int i = tid + 256 * q; myk[q] = (i < nns) ? ck[i] : 0ull; myr[q] = 0; }
    for (int j = 0; j < nns; ++j) {
        ull kj = ck[j];
#pragma unroll
        for (int q = 0; q < 6; ++q) myr[q] += (kj > myk[q]) ? 1 : 0;
    }
#pragma unroll
    for (int q = 0; q < 6; ++q) {
        int i = tid + 256 * q;
        if (i < nns && myr[q] < KTOP) {
            uint32_t idx = ~(uint32_t)myk[q];
            int r = myr[q];
            ns_idx[b * KTOP + r] = idx;
            ns_g[b * KTOP + r] = cg_l[i];
            int c = idx / OHW, rr = idx % OHW, s = rr / OH, t = rr % OH;
            ns_pk[b * KTOP + r] = (uint32_t)((c << 12) | (s << 6) | t);
        }
    }
}

// ---------------- one line-search attempt over the 512-entry pool ----------------
// grid (NATT, NB). Each thread owns 2 pool entries; one 512-iter broadcast rank
// loop gives exact global ranks (unique composite keys). rank<256 -> selected.
__global__ __launch_bounds__(256) void k_attempt(
    const float* __restrict__ Y, const float* __restrict__ W,
    const int* __restrict__ support_cnt, const uint32_t* __restrict__ support_idx,
    const float* __restrict__ support_val,
    const float* __restrict__ sup_g, const uint32_t* __restrict__ sup_pk,
    const uint32_t* __restrict__ ns_idx, const float* __restrict__ ns_g,
    const uint32_t* __restrict__ ns_pk,
    uint32_t* __restrict__ sel_idx, float* __restrict__ sel_val, double* __restrict__ err)
{
    int a = blockIdx.x, b = blockIdx.y, tid = threadIdx.x;
    int lane = tid & 63, wid = tid >> 6;
    float alpha = ldexpf(1.f, -a);
    int n = support_cnt[b];

    __shared__ ull ku[512];
    __shared__ uint32_t s_ci[KTOP];
    __shared__ float s_v[KTOP];
    __shared__ uint32_t s_pk[KTOP];
    __shared__ float recon[64 * RSTRIDE];
    __shared__ double redd[4];

    // pool entry A: non-support (v = alpha*g exactly; order alpha-invariant)
    uint32_t nsi = ns_idx[b * KTOP + tid];
    float v_ns = alpha * ns_g[b * KTOP + tid];
    uint32_t pk_ns = ns_pk[b * KTOP + tid];
    ull k_ns = ((ull)(__float_as_uint(v_ns) & 0x7fffffffu) << 32) | (ull)(uint32_t)(~nsi);
    ku[tid] = k_ns;
    // pool entry B: support (v = fmaf(alpha,g,x); alpha*g exact -> single round like ref)
    uint32_t spi; float v_sup; uint32_t pk_sup;
    if (tid < n) {
        spi = support_idx[b * KTOP + tid];
        v_sup = fmaf(alpha, sup_g[b * KTOP + tid], support_val[b * KTOP + tid]);
        pk_sup = sup_pk[b * KTOP + tid];
    } else {
        spi = (uint32_t)(CHW + tid);   // dummy: unique fake idx, |v|=0 -> never selected
        v_sup = 0.f; pk_sup = 0u;
    }
    ull k_sup = ((ull)(__float_as_uint(v_sup) & 0x7fffffffu) << 32) | (ull)(uint32_t)(~spi);
    ku[256 + tid] = k_sup;
    s_v[tid] = 0.f; s_ci[tid] = 0u; s_pk[tid] = 0u;
    for (int i = tid; i < 64 * RSTRIDE; i += 256) recon[i] = 0.f;
    __syncthreads();   // barrier 1

    int c_ns = 0, c_sup = 0;
    for (int j = 0; j < 512; ++j) {
        ull kj = ku[j];                 // same-address broadcast read, conflict-free
        c_ns += (kj > k_ns) ? 1 : 0;
        c_sup += (kj > k_sup) ? 1 : 0;
    }
    if (c_ns < KTOP) { s_ci[c_ns] = nsi; s_v[c_ns] = v_ns; s_pk[c_ns] = pk_ns; }
    if (c_sup < KTOP) { s_ci[c_sup] = spi; s_v[c_sup] = v_sup; s_pk[c_sup] = pk_sup; }
    __syncthreads();   // barrier 2

    sel_idx[((size_t)a * NB + b) * KTOP + tid] = s_ci[tid];
    sel_val[((size_t)a * NB + b) * KTOP + tid] = s_v[tid];

    // reconstruction scatter (per wave: 1 candidate, lanes = 64 taps)
    for (int task = tid; task < KTOP * 64; task += 256) {
        int i = task >> 6, tap = task & 63, p = tap >> 3, q = tap & 7;
        uint32_t pk = s_pk[i];
        float val = s_v[i];
        int c = pk >> 12, s = (pk >> 6) & 63, t = pk & 63;
        atomicAdd(&recon[(s + p) * RSTRIDE + (t + q)], val * W[c * 64 + tap]);
    }
    __syncthreads();   // barrier 3

    double accd = 0.0;
    for (int e = tid; e < IMG2; e += 256) {
        float d = Y[b * IMG2 + e] - recon[(e >> 6) * RSTRIDE + (e & 63)];
        accd += (double)d * (double)d;
    }
    for (int d = 32; d > 0; d >>= 1) accd += __shfl_xor(accd, d, 64);
    if (lane == 0) redd[wid] = accd;
    __syncthreads();   // barrier 4
    if (tid == 0) err[a * NB + b] = ((redd[0] + redd[1]) + redd[2]) + redd[3];
}

// ---------------- adopt selected attempt as new X (fused alpha-select + rank sort) ----------------
__global__ __launch_bounds__(256) void k_update(
    const double* __restrict__ l2part, const double* __restrict__ err,
    const uint32_t* __restrict__ sel_idx, const float* __restrict__ sel_val,
    int* __restrict__ support_cnt, uint32_t* __restrict__ support_idx, float* __restrict__ support_val)
{
    int b = blockIdx.x, tid = threadIdx.x;
    __shared__ double esum[NATT + 1];
    __shared__ int sel_sh;
    if (tid < NATT) {
        double e = 0.0;
        for (int b2 = 0; b2 < NB; ++b2) e += err[tid * NB + b2];
        esum[tid] = e;
    } else if (tid == NATT) {
        double l2 = 0.0;
        for (int b2 = 0; b2 < NB; ++b2) l2 += l2part[b2];
        esum[NATT] = l2;
    }
    __syncthreads();
    if (tid == 0) {
        double l2 = esum[NATT];
        int sel = NATT - 1;
        for (int a2 = 0; a2 < NATT; ++a2) if (esum[a2] < l2) { sel = a2; break; }
        sel_sh = sel;
    }
    __syncthreads();
    int a = sel_sh;
    __shared__ uint32_t ki[KTOP];
    __shared__ float kv[KTOP];
    ki[tid] = sel_idx[((size_t)a * NB + b) * KTOP + tid];
    kv[tid] = sel_val[((size_t)a * NB + b) * KTOP + tid];
    __syncthreads();
    uint32_t me = ki[tid];
    int rank = 0;
    for (int j = 0; j < KTOP; ++j) rank += (ki[j] < me) ? 1 : 0;
    support_idx[b * KTOP + rank] = me;
    support_val[b * KTOP + rank] = kv[tid];
    if (tid == 0) support_cnt[b] = KTOP;
}

// ---------------- final output: zero + scatter ----------------
__global__ void k_outzero(float4* __restrict__ out) {
    int i = blockIdx.x * 256 + threadIdx.x;
    if (i < (NB * CHW) / 4) out[i] = make_float4(0.f, 0.f, 0.f, 0.f);
}

__global__ void k_scatter(const uint32_t* __restrict__ support_idx, const float* __restrict__ support_val,
                          float* __restrict__ out) {
    int b = blockIdx.x, tid = threadIdx.x;
    if (tid < KTOP) out[(size_t)b * CHW + support_idx[b * KTOP + tid]] = support_val[b * KTOP + tid];
}

// ---------------- host ----------------
static size_t align256(size_t x) { return (x + 255) & ~(size_t)255; }

extern "C" void kernel_launch(void* const* d_in, const int* in_sizes, int n_in,
                              void* d_out, int out_size, void* d_ws, size_t ws_size,
                              hipStream_t stream)
{
    const float* Y = (const float*)d_in[0];   // (32,1,64,64)
    const float* W = (const float*)d_in[1];   // (128,1,8,8), normalized
    float* out = (float*)d_out;               // (32,128,57,57) — doubles as dense g

    char* p = (char*)d_ws;
    size_t off = 0;
    auto carve = [&](size_t bytes) { void* r = p + off; off = align256(off + bytes); return r; };
    float*    Rg          = (float*)   carve(NB * IMG2 * sizeof(float));
    uint32_t* hist        = (uint32_t*)carve((size_t)NB * NBUCK * sizeof(uint32_t));
    uint32_t* thr         = (uint32_t*)carve(NB * sizeof(uint32_t));
    int*      cand_cnt    = (int*)     carve(NB * NS * sizeof(int));
    double*   l2part      = (double*)  carve(NB * sizeof(double));
    double*   err         = (double*)  carve(NATT * NB * sizeof(double));
    int*      support_cnt = (int*)     carve(NB * sizeof(int));
    uint32_t* support_idx = (uint32_t*)carve(NB * KTOP * sizeof(uint32_t));
    float*    support_val = (float*)   carve(NB * KTOP * sizeof(float));
    uint32_t* sel_idx     = (uint32_t*)carve((size_t)NATT * NB * KTOP * sizeof(uint32_t));
    float*    sel_val     = (float*)   carve((size_t)NATT * NB * KTOP * sizeof(float));
    uint32_t* cand_idx    = (uint32_t*)carve((size_t)NB * NS * SCAP * sizeof(uint32_t));
    float*    cand_g      = (float*)   carve((size_t)NB * NS * SCAP * sizeof(float));
    uint32_t* ns_idx      = (uint32_t*)carve(NB * KTOP * sizeof(uint32_t));
    float*    ns_gbuf     = (float*)   carve(NB * KTOP * sizeof(float));
    uint32_t* ns_pk       = (uint32_t*)carve(NB * KTOP * sizeof(uint32_t));
    float*    sup_gbuf    = (float*)   carve(NB * KTOP * sizeof(float));
    uint32_t* sup_pk      = (uint32_t*)carve(NB * KTOP * sizeof(uint32_t));
    (void)ws_size; (void)in_sizes; (void)n_in; (void)out_size;

    k_init<<<1, 64, 0, stream>>>(support_cnt);
    for (int t = 0; t < 3; ++t) {
        k_resid<<<NB + NZB, 256, 0, stream>>>(Y, W, support_cnt, support_idx, support_val,
                                              Rg, l2part, hist, cand_cnt);
        k_conv<<<dim3(NB, 16), 256, 0, stream>>>(Rg, W, out, hist);
        k_thresh<<<NB, 256, 0, stream>>>(hist, thr);
        k_collect<<<dim3((CHW / 4 + 255) / 256, NB), 256, 0, stream>>>(out, thr, cand_cnt, cand_idx, cand_g);
        k_suppg<<<NB, 256, 0, stream>>>(out, support_cnt, support_idx, support_val,
                                        cand_cnt, cand_idx, cand_g,
                                        ns_idx, ns_gbuf, ns_pk, sup_gbuf, sup_pk);
        k_attempt<<<dim3(NATT, NB), 256, 0, stream>>>(Y, W, support_cnt, support_idx, support_val,
                                                      sup_gbuf, sup_pk, ns_idx, ns_gbuf, ns_pk,
                                                      sel_idx, sel_val, err);
        k_update<<<NB, 256, 0, stream>>>(l2part, err, sel_idx, sel_val,
                                         support_cnt, support_idx, support_val);
    }
    k_outzero<<<((NB * CHW) / 4 + 255) / 256, 256, 0, stream>>>((float4*)out);
    k_scatter<<<NB, 256, 0, stream>>>(support_idx, support_val, out);
}

// Round 8
// 695.593 us; speedup vs baseline: 1.1541x; 1.1541x over previous
//
#include <hip/hip_runtime.h>
#include <stdint.h>

// ---- problem constants ----
#define NB   32        // batch
#define NCH  128       // num atoms
#define IMG  64
#define IMG2 4096      // 64*64
#define OH   57        // 64-8+1
#define OHW  3249      // 57*57
#define CHW  415872    // 128*3249 (per-sample code size)
#define KTOP 256       // sparsity K
#define NATT 17        // alphas 2^0 .. 2^-16 (while count<=15 semantics)
#define NS   32        // candidate counter slices per sample (atomic spread)
#define SCAP 512       // capacity per slice
#define NCAP 1536      // collected (non-support) cap in k_suppg
#define NBUCK 8192     // |g| histogram buckets (top 13 bits: sign+exp8+mant4)
#define HSHIFT 18      // bits >> 18 -> bucket
#define TGT  512       // keep at least top-512 of |g| (superset of top-256 non-support)
#define RSTRIDE 72     // recon LDS row stride (2-way banks, free)
#define NZB  257       // zero-blocks fused into k_resid (256 hist + 1 cand_cnt)
#define BMW  12996     // bitmap words for CHW bits (415872/32)

typedef unsigned long long ull;

// ---------------- init: support count = 0 ----------------
__global__ void k_init(int* support_cnt) {
    if (threadIdx.x < NB) support_cnt[threadIdx.x] = 0;
}

// ---------------- R = Y - D*X (sparse scatter) + fused zeroing ----------------
__global__ __launch_bounds__(256) void k_resid(
    const float* __restrict__ Y, const float* __restrict__ W,
    const int* __restrict__ support_cnt, const uint32_t* __restrict__ support_idx,
    const float* __restrict__ support_val, float* __restrict__ Rg, double* __restrict__ l2part,
    uint32_t* __restrict__ hist, int* __restrict__ cand_cnt)
{
    int bx = blockIdx.x, tid = threadIdx.x;
    if (bx >= NB) {
        int zb = bx - NB;
        if (zb < 256) {
            ((uint4*)hist)[zb * 256 + tid] = make_uint4(0u, 0u, 0u, 0u);
        } else {
            ((uint4*)cand_cnt)[tid] = make_uint4(0u, 0u, 0u, 0u);
        }
        return;
    }
    int b = bx;
    __shared__ float Rs[IMG2];
    const float4* Y4 = (const float4*)(Y + b * IMG2);
    float4* R4 = (float4*)Rs;
    for (int i = tid; i < IMG2 / 4; i += 256) R4[i] = Y4[i];
    __syncthreads();
    int n = support_cnt[b];
    for (int task = tid; task < n * 64; task += 256) {
        int i = task >> 6, tap = task & 63, p = tap >> 3, q = tap & 7;
        uint32_t idx = support_idx[b * KTOP + i];
        float val = support_val[b * KTOP + i];
        int c = idx / OHW, rem = idx % OHW, s = rem / OH, t = rem % OH;
        float w = W[c * 64 + p * 8 + q];
        atomicAdd(&Rs[(s + p) * IMG + (t + q)], -val * w);
    }
    __syncthreads();
    double acc = 0.0;
    for (int i = tid; i < IMG2; i += 256) {
        float v = Rs[i];
        Rg[b * IMG2 + i] = v;
        acc += (double)v * (double)v;
    }
    __shared__ double red[256];
    red[tid] = acc; __syncthreads();
    for (int s2 = 128; s2 > 0; s2 >>= 1) { if (tid < s2) red[tid] += red[tid + s2]; __syncthreads(); }
    if (tid == 0) l2part[b] = red[0];
}

// ---------------- g = D^T * R (dense) + fine |g| histogram ----------------
__global__ __launch_bounds__(256) void k_conv(
    const float* __restrict__ Rg, const float* __restrict__ W,
    float* __restrict__ g_out, uint32_t* __restrict__ hist)
{
    int b = blockIdx.x, cg0 = blockIdx.y, tid = threadIdx.x;
    __shared__ float Rs[71 * 72];
    __shared__ uint32_t hl[NBUCK];
    for (int i = tid; i < 71 * 72; i += 256) Rs[i] = 0.f;
    for (int i = tid; i < NBUCK; i += 256) hl[i] = 0u;
    __syncthreads();
    const float4* R4 = (const float4*)(Rg + b * IMG2);
    for (int i = tid; i < 1024; i += 256) {
        int row = i >> 4, col4 = (i & 15) * 4;
        *(float4*)&Rs[row * 72 + col4] = R4[i];
    }
    __syncthreads();
    int csub = tid >> 7;
    int tile = tid & 127;
    bool active = tile < 120;
    int tr = active ? tile / 15 : 0;
    int tc = active ? tile % 15 : 0;
    int s0 = tr * 8, t0 = tc * 4;

    for (int sub = 0; sub < 4; ++sub) {
        int c = cg0 * 8 + sub * 2 + csub;
        int c_s = __builtin_amdgcn_readfirstlane(c);
        const float* Wc = W + c_s * 64;

        float acc[8][4];
#pragma unroll
        for (int r = 0; r < 8; ++r)
#pragma unroll
            for (int cc = 0; cc < 4; ++cc) acc[r][cc] = 0.f;

#pragma unroll
        for (int rho = 0; rho < 15; ++rho) {
            float rb[12];
            const float* rp = &Rs[(s0 + rho) * 72 + t0];
            *(float4*)&rb[0] = *(const float4*)rp;
            *(float4*)&rb[4] = *(const float4*)(rp + 4);
            *(float4*)&rb[8] = *(const float4*)(rp + 8);
#pragma unroll
            for (int r = 0; r < 8; ++r) {
                const int p = rho - r;
                if (p >= 0 && p < 8) {
#pragma unroll
                    for (int q = 0; q < 8; ++q) {
                        float wv = Wc[q * 8 + p];
#pragma unroll
                        for (int cc = 0; cc < 4; ++cc)
                            acc[r][cc] = fmaf(rb[cc + q], wv, acc[r][cc]);
                    }
                }
            }
        }
        if (active) {
            float* go = g_out + (size_t)(b * NCH + c) * OHW;
#pragma unroll
            for (int r = 0; r < 8; ++r) {
                int s = s0 + r;
                if (s < OH) {
#pragma unroll
                    for (int cc = 0; cc < 4; ++cc) {
                        int t = t0 + cc;
                        if (t < OH) {
                            float v = acc[r][cc];
                            go[s * OH + t] = v;
                            uint32_t bits = __float_as_uint(v) & 0x7fffffffu;
                            atomicAdd(&hl[bits >> HSHIFT], 1u);
                        }
                    }
                }
            }
        }
    }
    __syncthreads();
    for (int i = tid; i < NBUCK; i += 256) {
        uint32_t v = hl[i];
        if (v) atomicAdd(&hist[b * NBUCK + i], v);
    }
}

// ---------------- per-sample bucket threshold (parallel suffix scan) ----------------
__global__ __launch_bounds__(256) void k_thresh(const uint32_t* __restrict__ hist,
                                                uint32_t* __restrict__ thr) {
    int b = blockIdx.x, tid = threadIdx.x;
    uint32_t h[32];
    uint32_t s = 0;
    const uint32_t* hb = hist + b * NBUCK + tid * 32;
#pragma unroll
    for (int k = 0; k < 32; ++k) { h[k] = hb[k]; s += h[k]; }
    __shared__ uint32_t buf[2][256];
    int cur = 0;
    buf[0][tid] = s;
    __syncthreads();
    for (int d = 1; d < 256; d <<= 1) {
        uint32_t v = buf[cur][tid];
        if (tid + d < 256) v += buf[cur][tid + d];
        buf[cur ^ 1][tid] = v;
        cur ^= 1;
        __syncthreads();
    }
    uint32_t sufme = buf[cur][tid];
    uint32_t base  = (tid < 255) ? buf[cur][tid + 1] : 0u;
    if (tid == 0 && buf[cur][0] < TGT) thr[b] = 0u;
    if (base < TGT && sufme >= TGT) {
        uint32_t acc = base; int bk = 0;
#pragma unroll
        for (int k = 31; k >= 0; --k) {
            acc += h[k];
            if (acc >= TGT) { bk = tid * 32 + k; break; }
        }
        thr[b] = (uint32_t)bk << HSHIFT;
    }
}

// ---------------- collect candidates: |g| above bucket threshold ----------------
__global__ __launch_bounds__(256) void k_collect(
    const float* __restrict__ g, const uint32_t* __restrict__ thr,
    int* __restrict__ cand_cnt, uint32_t* __restrict__ cand_idx, float* __restrict__ cand_g)
{
    int b = blockIdx.y;
    int i4 = blockIdx.x * 256 + threadIdx.x;
    if (i4 >= CHW / 4) return;
    int slice = blockIdx.x & (NS - 1);
    uint32_t tb = thr[b];
    float4 v4 = ((const float4*)(g + (size_t)b * CHW))[i4];
    float vv[4] = { v4.x, v4.y, v4.z, v4.w };
#pragma unroll
    for (int k = 0; k < 4; ++k) {
        uint32_t bits = __float_as_uint(vv[k]) & 0x7fffffffu;
        if (bits >= tb) {
            int pos = atomicAdd(&cand_cnt[b * NS + slice], 1);
            if (pos < SCAP) {
                cand_idx[(b * NS + slice) * SCAP + pos] = (uint32_t)(i4 * 4 + k);
                cand_g[(b * NS + slice) * SCAP + pos] = vv[k];
            }
        }
    }
}

// ---------------- build per-sample pools (LDS bitmap membership, 1024 thr) ----------------
__global__ __launch_bounds__(1024) void k_suppg(
    const float* __restrict__ g,
    const int* __restrict__ support_cnt, const uint32_t* __restrict__ support_idx,
    const int* __restrict__ cand_cnt, const uint32_t* __restrict__ cand_idx,
    const float* __restrict__ cand_g,
    uint32_t* __restrict__ ns_idx, float* __restrict__ ns_g, uint32_t* __restrict__ ns_pk,
    float* __restrict__ sup_g, uint32_t* __restrict__ sup_pk)
{
    int b = blockIdx.x, tid = threadIdx.x, lane = tid & 63;
    __shared__ uint32_t bm[BMW];
    __shared__ int cnts[NS];
    __shared__ ull ck[NCAP];
    __shared__ float cg_l[NCAP];
    __shared__ int nns_sh;
    int n = support_cnt[b];
    for (int i = tid; i < BMW / 4; i += 1024) ((uint4*)bm)[i] = make_uint4(0u, 0u, 0u, 0u);
    if (tid < NS) cnts[tid] = min(cand_cnt[b * NS + tid], SCAP);
    if (tid == 0) nns_sh = 0;
    __syncthreads();
    // mark support membership + emit support g / packed coords
    if (tid < KTOP) {
        if (tid < n) {
            uint32_t idx = support_idx[b * KTOP + tid];
            atomicOr(&bm[idx >> 5], 1u << (idx & 31));
            float gv = g[(size_t)b * CHW + idx];
            sup_g[b * KTOP + tid] = gv;
            int c = idx / OHW, r = idx % OHW, s = r / OH, t = r % OH;
            sup_pk[b * KTOP + tid] = (uint32_t)((c << 12) | (s << 6) | t);
        } else {
            sup_g[b * KTOP + tid] = 0.f;
            sup_pk[b * KTOP + tid] = 0u;
        }
    }
    __syncthreads();
    // compact collected slices into LDS, filtering support via bitmap (O(1))
    for (int t0 = tid; t0 < NS * SCAP; t0 += 1024) {
        int s = t0 >> 9, j = t0 & (SCAP - 1);
        bool keep = false; uint32_t idx = 0; float gv = 0.f;
        if (j < cnts[s]) {
            idx = cand_idx[(b * NS + s) * SCAP + j];
            gv = cand_g[(b * NS + s) * SCAP + j];
            keep = ((bm[idx >> 5] >> (idx & 31)) & 1u) == 0u;
        }
        ull mk = __ballot(keep);
        if (mk) {
            int basep = 0;
            if (lane == 0) basep = atomicAdd(&nns_sh, (int)__popcll(mk));
            basep = __shfl(basep, 0, 64);
            if (keep) {
                int p = basep + (int)__popcll(mk & ((1ull << lane) - 1ull));
                if (p < NCAP) {
                    ck[p] = ((ull)(__float_as_uint(gv) & 0x7fffffffu) << 32) | (ull)(uint32_t)(~idx);
                    cg_l[p] = gv;
                }
            }
        }
    }
    __syncthreads();
    int nns = min(nns_sh, NCAP);
    // exact rank among collected non-support (|g| desc, idx asc); rank<256 -> sorted out
    ull myk[2]; int myr[2];
#pragma unroll
    for (int q = 0; q < 2; ++q) { int i = tid + 1024 * q; myk[q] = (i < nns) ? ck[i] : 0ull; myr[q] = 0; }
    for (int j = 0; j < nns; ++j) {
        ull kj = ck[j];
#pragma unroll
        for (int q = 0; q < 2; ++q) myr[q] += (kj > myk[q]) ? 1 : 0;
    }
#pragma unroll
    for (int q = 0; q < 2; ++q) {
        int i = tid + 1024 * q;
        if (i < nns && myr[q] < KTOP) {
            uint32_t idx = ~(uint32_t)myk[q];
            int r = myr[q];
            ns_idx[b * KTOP + r] = idx;
            ns_g[b * KTOP + r] = cg_l[i];
            int c = idx / OHW, rr = idx % OHW, s = rr / OH, t = rr % OH;
            ns_pk[b * KTOP + r] = (uint32_t)((c << 12) | (s << 6) | t);
        }
    }
}

// ---------------- selection only: exact top-256 over the 512-entry pool ----------------
__global__ __launch_bounds__(256) void k_sel(
    const int* __restrict__ support_cnt, const uint32_t* __restrict__ support_idx,
    const float* __restrict__ support_val,
    const float* __restrict__ sup_g, const uint32_t* __restrict__ sup_pk,
    const uint32_t* __restrict__ ns_idx, const float* __restrict__ ns_g,
    const uint32_t* __restrict__ ns_pk,
    uint32_t* __restrict__ sel_idx, float* __restrict__ sel_val, uint32_t* __restrict__ sel_pk)
{
    int a = blockIdx.x, b = blockIdx.y, tid = threadIdx.x;
    float alpha = ldexpf(1.f, -a);
    int n = support_cnt[b];

    __shared__ ull ku[512];
    __shared__ uint32_t s_ci[KTOP];
    __shared__ float s_v[KTOP];
    __shared__ uint32_t s_pk[KTOP];

    uint32_t nsi = ns_idx[b * KTOP + tid];
    float v_ns = alpha * ns_g[b * KTOP + tid];
    uint32_t pk_ns = ns_pk[b * KTOP + tid];
    ull k_ns = ((ull)(__float_as_uint(v_ns) & 0x7fffffffu) << 32) | (ull)(uint32_t)(~nsi);
    ku[tid] = k_ns;
    uint32_t spi; float v_sup; uint32_t pk_sup;
    if (tid < n) {
        spi = support_idx[b * KTOP + tid];
        v_sup = fmaf(alpha, sup_g[b * KTOP + tid], support_val[b * KTOP + tid]);
        pk_sup = sup_pk[b * KTOP + tid];
    } else {
        spi = (uint32_t)(CHW + tid);   // dummy unique idx, |v|=0 -> never selected
        v_sup = 0.f; pk_sup = 0u;
    }
    ull k_sup = ((ull)(__float_as_uint(v_sup) & 0x7fffffffu) << 32) | (ull)(uint32_t)(~spi);
    ku[256 + tid] = k_sup;
    __syncthreads();

    int c_ns = 0, c_sup = 0;
    for (int j = 0; j < 512; ++j) {
        ull kj = ku[j];                 // broadcast read, conflict-free
        c_ns += (kj > k_ns) ? 1 : 0;
        c_sup += (kj > k_sup) ? 1 : 0;
    }
    if (c_ns < KTOP) { s_ci[c_ns] = nsi; s_v[c_ns] = v_ns; s_pk[c_ns] = pk_ns; }
    if (c_sup < KTOP) { s_ci[c_sup] = spi; s_v[c_sup] = v_sup; s_pk[c_sup] = pk_sup; }
    __syncthreads();

    size_t o = ((size_t)a * NB + b) * KTOP + tid;
    sel_idx[o] = s_ci[tid];
    sel_val[o] = s_v[tid];
    sel_pk[o] = s_pk[tid];
}

// ---------------- recon + err per (alpha,b): 1024 threads for latency hiding ----------------
__global__ __launch_bounds__(1024) void k_err(
    const float* __restrict__ Y, const float* __restrict__ W,
    const float* __restrict__ sel_val, const uint32_t* __restrict__ sel_pk,
    double* __restrict__ err)
{
    int a = blockIdx.x, b = blockIdx.y, tid = threadIdx.x;
    int lane = tid & 63, wid = tid >> 6;
    __shared__ float recon[64 * RSTRIDE];
    __shared__ float s_v[KTOP];
    __shared__ uint32_t s_pk[KTOP];
    __shared__ double redd[16];

    for (int i = tid; i < 64 * RSTRIDE; i += 1024) recon[i] = 0.f;
    if (tid < KTOP) {
        size_t o = ((size_t)a * NB + b) * KTOP + tid;
        s_v[tid] = sel_val[o];
        s_pk[tid] = sel_pk[o];
    }
    __syncthreads();
    // scatter: 16 iterations/thread; i uniform per wave per iteration
    for (int task = tid; task < KTOP * 64; task += 1024) {
        int i = task >> 6, tap = task & 63, p = tap >> 3, q = tap & 7;
        uint32_t pk = s_pk[i];
        float val = s_v[i];
        int c = pk >> 12, s = (pk >> 6) & 63, t = pk & 63;
        atomicAdd(&recon[(s + p) * RSTRIDE + (t + q)], val * W[c * 64 + tap]);
    }
    __syncthreads();
    // err: one float4 per thread
    float4 y4 = ((const float4*)(Y + b * IMG2))[tid];
    int row = tid >> 4, col = (tid & 15) * 4;
    const float* rr = &recon[row * RSTRIDE + col];
    double accd = 0.0;
    float d0 = y4.x - rr[0]; accd += (double)d0 * (double)d0;
    float d1 = y4.y - rr[1]; accd += (double)d1 * (double)d1;
    float d2 = y4.z - rr[2]; accd += (double)d2 * (double)d2;
    float d3 = y4.w - rr[3]; accd += (double)d3 * (double)d3;
    for (int d = 32; d > 0; d >>= 1) accd += __shfl_xor(accd, d, 64);
    if (lane == 0) redd[wid] = accd;
    __syncthreads();
    if (tid == 0) {
        double e = 0.0;
#pragma unroll
        for (int w2 = 0; w2 < 16; ++w2) e += redd[w2];
        err[a * NB + b] = e;
    }
}

// ---------------- adopt selected attempt as new X (fused alpha-select + rank sort) ----------------
__global__ __launch_bounds__(256) void k_update(
    const double* __restrict__ l2part, const double* __restrict__ err,
    const uint32_t* __restrict__ sel_idx, const float* __restrict__ sel_val,
    int* __restrict__ support_cnt, uint32_t* __restrict__ support_idx, float* __restrict__ support_val)
{
    int b = blockIdx.x, tid = threadIdx.x;
    __shared__ double esum[NATT + 1];
    __shared__ int sel_sh;
    if (tid < NATT) {
        double e = 0.0;
        for (int b2 = 0; b2 < NB; ++b2) e += err[tid * NB + b2];
        esum[tid] = e;
    } else if (tid == NATT) {
        double l2 = 0.0;
        for (int b2 = 0; b2 < NB; ++b2) l2 += l2part[b2];
        esum[NATT] = l2;
    }
    __syncthreads();
    if (tid == 0) {
        double l2 = esum[NATT];
        int sel = NATT - 1;
        for (int a2 = 0; a2 < NATT; ++a2) if (esum[a2] < l2) { sel = a2; break; }
        sel_sh = sel;
    }
    __syncthreads();
    int a = sel_sh;
    __shared__ uint32_t ki[KTOP];
    __shared__ float kv[KTOP];
    ki[tid] = sel_idx[((size_t)a * NB + b) * KTOP + tid];
    kv[tid] = sel_val[((size_t)a * NB + b) * KTOP + tid];
    __syncthreads();
    uint32_t me = ki[tid];
    int rank = 0;
    for (int j = 0; j < KTOP; ++j) rank += (ki[j] < me) ? 1 : 0;
    support_idx[b * KTOP + rank] = me;
    support_val[b * KTOP + rank] = kv[tid];
    if (tid == 0) support_cnt[b] = KTOP;
}

// ---------------- final output: zero + scatter ----------------
__global__ void k_outzero(float4* __restrict__ out) {
    int i = blockIdx.x * 256 + threadIdx.x;
    if (i < (NB * CHW) / 4) out[i] = make_float4(0.f, 0.f, 0.f, 0.f);
}

__global__ void k_scatter(const uint32_t* __restrict__ support_idx, const float* __restrict__ support_val,
                          float* __restrict__ out) {
    int b = blockIdx.x, tid = threadIdx.x;
    if (tid < KTOP) out[(size_t)b * CHW + support_idx[b * KTOP + tid]] = support_val[b * KTOP + tid];
}

// ---------------- host ----------------
static size_t align256(size_t x) { return (x + 255) & ~(size_t)255; }

extern "C" void kernel_launch(void* const* d_in, const int* in_sizes, int n_in,
                              void* d_out, int out_size, void* d_ws, size_t ws_size,
                              hipStream_t stream)
{
    const float* Y = (const float*)d_in[0];   // (32,1,64,64)
    const float* W = (const float*)d_in[1];   // (128,1,8,8), normalized
    float* out = (float*)d_out;               // (32,128,57,57) — doubles as dense g

    char* p = (char*)d_ws;
    size_t off = 0;
    auto carve = [&](size_t bytes) { void* r = p + off; off = align256(off + bytes); return r; };
    float*    Rg          = (float*)   carve(NB * IMG2 * sizeof(float));
    uint32_t* hist        = (uint32_t*)carve((size_t)NB * NBUCK * sizeof(uint32_t));
    uint32_t* thr         = (uint32_t*)carve(NB * sizeof(uint32_t));
    int*      cand_cnt    = (int*)     carve(NB * NS * sizeof(int));
    double*   l2part      = (double*)  carve(NB * sizeof(double));
    double*   err         = (double*)  carve(NATT * NB * sizeof(double));
    int*      support_cnt = (int*)     carve(NB * sizeof(int));
    uint32_t* support_idx = (uint32_t*)carve(NB * KTOP * sizeof(uint32_t));
    float*    support_val = (float*)   carve(NB * KTOP * sizeof(float));
    uint32_t* sel_idx     = (uint32_t*)carve((size_t)NATT * NB * KTOP * sizeof(uint32_t));
    float*    sel_val     = (float*)   carve((size_t)NATT * NB * KTOP * sizeof(float));
    uint32_t* sel_pk      = (uint32_t*)carve((size_t)NATT * NB * KTOP * sizeof(uint32_t));
    uint32_t* cand_idx    = (uint32_t*)carve((size_t)NB * NS * SCAP * sizeof(uint32_t));
    float*    cand_g      = (float*)   carve((size_t)NB * NS * SCAP * sizeof(float));
    uint32_t* ns_idx      = (uint32_t*)carve(NB * KTOP * sizeof(uint32_t));
    float*    ns_gbuf     = (float*)   carve(NB * KTOP * sizeof(float));
    uint32_t* ns_pk       = (uint32_t*)carve(NB * KTOP * sizeof(uint32_t));
    float*    sup_gbuf    = (float*)   carve(NB * KTOP * sizeof(float));
    uint32_t* sup_pk      = (uint32_t*)carve(NB * KTOP * sizeof(uint32_t));
    (void)ws_size; (void)in_sizes; (void)n_in; (void)out_size;

    k_init<<<1, 64, 0, stream>>>(support_cnt);
    for (int t = 0; t < 3; ++t) {
        k_resid<<<NB + NZB, 256, 0, stream>>>(Y, W, support_cnt, support_idx, support_val,
                                              Rg, l2part, hist, cand_cnt);
        k_conv<<<dim3(NB, 16), 256, 0, stream>>>(Rg, W, out, hist);
        k_thresh<<<NB, 256, 0, stream>>>(hist, thr);
        k_collect<<<dim3((CHW / 4 + 255) / 256, NB), 256, 0, stream>>>(out, thr, cand_cnt, cand_idx, cand_g);
        k_suppg<<<NB, 1024, 0, stream>>>(out, support_cnt, support_idx,
                                         cand_cnt, cand_idx, cand_g,
                                         ns_idx, ns_gbuf, ns_pk, sup_gbuf, sup_pk);
        k_sel<<<dim3(NATT, NB), 256, 0, stream>>>(support_cnt, support_idx, support_val,
                                                  sup_gbuf, sup_pk, ns_idx, ns_gbuf, ns_pk,
                                                  sel_idx, sel_val, sel_pk);
        k_err<<<dim3(NATT, NB), 1024, 0, stream>>>(Y, W, sel_val, sel_pk, err);
        k_update<<<NB, 256, 0, stream>>>(l2part, err, sel_idx, sel_val,
                                         support_cnt, support_idx, support_val);
    }
    k_outzero<<<((NB * CHW) / 4 + 255) / 256, 256, 0, stream>>>((float4*)out);
    k_scatter<<<NB, 256, 0, stream>>>(support_idx, support_val, out);
}

// Round 9
// 670.959 us; speedup vs baseline: 1.1964x; 1.0367x over previous
//
#include <hip/hip_runtime.h>
#include <stdint.h>

// ---- problem constants ----
#define NB   32        // batch
#define NCH  128       // num atoms
#define IMG  64
#define IMG2 4096      // 64*64
#define OH   57        // 64-8+1
#define OHW  3249      // 57*57
#define CHW  415872    // 128*3249 (per-sample code size)
#define KTOP 256       // sparsity K
#define NATT 17        // alphas 2^0 .. 2^-16 (while count<=15 semantics)
#define NS   32        // candidate counter slices per sample (atomic spread)
#define SCAP 512       // capacity per slice
#define NCAP 1536      // collected (non-support) cap in k_suppg
#define NBUCK 8192     // |g| histogram buckets (top 13 bits: sign+exp8+mant4)
#define HSHIFT 18      // bits >> 18 -> bucket
#define TGT  512       // keep at least top-512 of |g| (superset of top-256 non-support)
#define RSTRIDE 72     // recon LDS row stride (2-way banks, free)
#define NZB  257       // zero-blocks fused into k_resid (256 hist + 1 cand_cnt)
#define BMW  12996     // bitmap words for CHW bits (415872/32)

typedef unsigned long long ull;

// ---------------- init: support count = 0 ----------------
__global__ void k_init(int* support_cnt) {
    if (threadIdx.x < NB) support_cnt[threadIdx.x] = 0;
}

// ---------------- R = Y - D*X (sparse scatter) + fused zeroing ----------------
__global__ __launch_bounds__(256) void k_resid(
    const float* __restrict__ Y, const float* __restrict__ W,
    const int* __restrict__ support_cnt, const uint32_t* __restrict__ support_idx,
    const float* __restrict__ support_val, float* __restrict__ Rg, double* __restrict__ l2part,
    uint32_t* __restrict__ hist, int* __restrict__ cand_cnt)
{
    int bx = blockIdx.x, tid = threadIdx.x;
    if (bx >= NB) {
        int zb = bx - NB;
        if (zb < 256) {
            ((uint4*)hist)[zb * 256 + tid] = make_uint4(0u, 0u, 0u, 0u);
        } else {
            ((uint4*)cand_cnt)[tid] = make_uint4(0u, 0u, 0u, 0u);
        }
        return;
    }
    int b = bx;
    __shared__ float Rs[IMG2];
    const float4* Y4 = (const float4*)(Y + b * IMG2);
    float4* R4 = (float4*)Rs;
    for (int i = tid; i < IMG2 / 4; i += 256) R4[i] = Y4[i];
    __syncthreads();
    int n = support_cnt[b];
    for (int task = tid; task < n * 64; task += 256) {
        int i = task >> 6, tap = task & 63, p = tap >> 3, q = tap & 7;
        uint32_t idx = support_idx[b * KTOP + i];
        float val = support_val[b * KTOP + i];
        int c = idx / OHW, rem = idx % OHW, s = rem / OH, t = rem % OH;
        float w = W[c * 64 + p * 8 + q];
        atomicAdd(&Rs[(s + p) * IMG + (t + q)], -val * w);
    }
    __syncthreads();
    double acc = 0.0;
    for (int i = tid; i < IMG2; i += 256) {
        float v = Rs[i];
        Rg[b * IMG2 + i] = v;
        acc += (double)v * (double)v;
    }
    __shared__ double red[256];
    red[tid] = acc; __syncthreads();
    for (int s2 = 128; s2 > 0; s2 >>= 1) { if (tid < s2) red[tid] += red[tid + s2]; __syncthreads(); }
    if (tid == 0) l2part[b] = red[0];
}

// ---------------- g = D^T * R (dense) + fine |g| histogram ----------------
__global__ __launch_bounds__(256) void k_conv(
    const float* __restrict__ Rg, const float* __restrict__ W,
    float* __restrict__ g_out, uint32_t* __restrict__ hist)
{
    int b = blockIdx.x, cg0 = blockIdx.y, tid = threadIdx.x;
    __shared__ float Rs[71 * 72];
    __shared__ uint32_t hl[NBUCK];
    for (int i = tid; i < 71 * 72; i += 256) Rs[i] = 0.f;
    for (int i = tid; i < NBUCK; i += 256) hl[i] = 0u;
    __syncthreads();
    const float4* R4 = (const float4*)(Rg + b * IMG2);
    for (int i = tid; i < 1024; i += 256) {
        int row = i >> 4, col4 = (i & 15) * 4;
        *(float4*)&Rs[row * 72 + col4] = R4[i];
    }
    __syncthreads();
    int csub = tid >> 7;
    int tile = tid & 127;
    bool active = tile < 120;
    int tr = active ? tile / 15 : 0;
    int tc = active ? tile % 15 : 0;
    int s0 = tr * 8, t0 = tc * 4;

    for (int sub = 0; sub < 4; ++sub) {
        int c = cg0 * 8 + sub * 2 + csub;
        int c_s = __builtin_amdgcn_readfirstlane(c);
        const float* Wc = W + c_s * 64;

        float acc[8][4];
#pragma unroll
        for (int r = 0; r < 8; ++r)
#pragma unroll
            for (int cc = 0; cc < 4; ++cc) acc[r][cc] = 0.f;

#pragma unroll
        for (int rho = 0; rho < 15; ++rho) {
            float rb[12];
            const float* rp = &Rs[(s0 + rho) * 72 + t0];
            *(float4*)&rb[0] = *(const float4*)rp;
            *(float4*)&rb[4] = *(const float4*)(rp + 4);
            *(float4*)&rb[8] = *(const float4*)(rp + 8);
#pragma unroll
            for (int r = 0; r < 8; ++r) {
                const int p = rho - r;
                if (p >= 0 && p < 8) {
#pragma unroll
                    for (int q = 0; q < 8; ++q) {
                        float wv = Wc[q * 8 + p];
#pragma unroll
                        for (int cc = 0; cc < 4; ++cc)
                            acc[r][cc] = fmaf(rb[cc + q], wv, acc[r][cc]);
                    }
                }
            }
        }
        if (active) {
            float* go = g_out + (size_t)(b * NCH + c) * OHW;
#pragma unroll
            for (int r = 0; r < 8; ++r) {
                int s = s0 + r;
                if (s < OH) {
#pragma unroll
                    for (int cc = 0; cc < 4; ++cc) {
                        int t = t0 + cc;
                        if (t < OH) {
                            float v = acc[r][cc];
                            go[s * OH + t] = v;
                            uint32_t bits = __float_as_uint(v) & 0x7fffffffu;
                            atomicAdd(&hl[bits >> HSHIFT], 1u);
                        }
                    }
                }
            }
        }
    }
    __syncthreads();
    for (int i = tid; i < NBUCK; i += 256) {
        uint32_t v = hl[i];
        if (v) atomicAdd(&hist[b * NBUCK + i], v);
    }
}

// ---------------- per-sample bucket threshold (parallel suffix scan) ----------------
__global__ __launch_bounds__(256) void k_thresh(const uint32_t* __restrict__ hist,
                                                uint32_t* __restrict__ thr) {
    int b = blockIdx.x, tid = threadIdx.x;
    uint32_t h[32];
    uint32_t s = 0;
    const uint32_t* hb = hist + b * NBUCK + tid * 32;
#pragma unroll
    for (int k = 0; k < 32; ++k) { h[k] = hb[k]; s += h[k]; }
    __shared__ uint32_t buf[2][256];
    int cur = 0;
    buf[0][tid] = s;
    __syncthreads();
    for (int d = 1; d < 256; d <<= 1) {
        uint32_t v = buf[cur][tid];
        if (tid + d < 256) v += buf[cur][tid + d];
        buf[cur ^ 1][tid] = v;
        cur ^= 1;
        __syncthreads();
    }
    uint32_t sufme = buf[cur][tid];
    uint32_t base  = (tid < 255) ? buf[cur][tid + 1] : 0u;
    if (tid == 0 && buf[cur][0] < TGT) thr[b] = 0u;
    if (base < TGT && sufme >= TGT) {
        uint32_t acc = base; int bk = 0;
#pragma unroll
        for (int k = 31; k >= 0; --k) {
            acc += h[k];
            if (acc >= TGT) { bk = tid * 32 + k; break; }
        }
        thr[b] = (uint32_t)bk << HSHIFT;
    }
}

// ---------------- collect candidates: |g| above bucket threshold ----------------
__global__ __launch_bounds__(256) void k_collect(
    const float* __restrict__ g, const uint32_t* __restrict__ thr,
    int* __restrict__ cand_cnt, uint32_t* __restrict__ cand_idx, float* __restrict__ cand_g)
{
    int b = blockIdx.y;
    int i4 = blockIdx.x * 256 + threadIdx.x;
    if (i4 >= CHW / 4) return;
    int slice = blockIdx.x & (NS - 1);
    uint32_t tb = thr[b];
    float4 v4 = ((const float4*)(g + (size_t)b * CHW))[i4];
    float vv[4] = { v4.x, v4.y, v4.z, v4.w };
#pragma unroll
    for (int k = 0; k < 4; ++k) {
        uint32_t bits = __float_as_uint(vv[k]) & 0x7fffffffu;
        if (bits >= tb) {
            int pos = atomicAdd(&cand_cnt[b * NS + slice], 1);
            if (pos < SCAP) {
                cand_idx[(b * NS + slice) * SCAP + pos] = (uint32_t)(i4 * 4 + k);
                cand_g[(b * NS + slice) * SCAP + pos] = vv[k];
            }
        }
    }
}

// ---------------- build per-sample pools (bitmap membership; batched rank) ----------------
__global__ __launch_bounds__(1024) void k_suppg(
    const float* __restrict__ g,
    const int* __restrict__ support_cnt, const uint32_t* __restrict__ support_idx,
    const int* __restrict__ cand_cnt, const uint32_t* __restrict__ cand_idx,
    const float* __restrict__ cand_g,
    uint32_t* __restrict__ ns_idx, float* __restrict__ ns_g, uint32_t* __restrict__ ns_pk,
    float* __restrict__ sup_g, uint32_t* __restrict__ sup_pk)
{
    int b = blockIdx.x, tid = threadIdx.x, lane = tid & 63;
    __shared__ uint32_t bm[BMW];
    __shared__ int cnts[NS];
    __shared__ ull ck[NCAP];
    __shared__ float cg_l[NCAP];
    __shared__ int nns_sh;
    int n = support_cnt[b];
    for (int i = tid; i < BMW / 4; i += 1024) ((uint4*)bm)[i] = make_uint4(0u, 0u, 0u, 0u);
    if (tid < NS) cnts[tid] = min(cand_cnt[b * NS + tid], SCAP);
    if (tid == 0) nns_sh = 0;
    __syncthreads();
    if (tid < KTOP) {
        if (tid < n) {
            uint32_t idx = support_idx[b * KTOP + tid];
            atomicOr(&bm[idx >> 5], 1u << (idx & 31));
            float gv = g[(size_t)b * CHW + idx];
            sup_g[b * KTOP + tid] = gv;
            int c = idx / OHW, r = idx % OHW, s = r / OH, t = r % OH;
            sup_pk[b * KTOP + tid] = (uint32_t)((c << 12) | (s << 6) | t);
        } else {
            sup_g[b * KTOP + tid] = 0.f;
            sup_pk[b * KTOP + tid] = 0u;
        }
    }
    __syncthreads();
    for (int t0 = tid; t0 < NS * SCAP; t0 += 1024) {
        int s = t0 >> 9, j = t0 & (SCAP - 1);
        bool keep = false; uint32_t idx = 0; float gv = 0.f;
        if (j < cnts[s]) {
            idx = cand_idx[(b * NS + s) * SCAP + j];
            gv = cand_g[(b * NS + s) * SCAP + j];
            keep = ((bm[idx >> 5] >> (idx & 31)) & 1u) == 0u;
        }
        ull mk = __ballot(keep);
        if (mk) {
            int basep = 0;
            if (lane == 0) basep = atomicAdd(&nns_sh, (int)__popcll(mk));
            basep = __shfl(basep, 0, 64);
            if (keep) {
                int p = basep + (int)__popcll(mk & ((1ull << lane) - 1ull));
                if (p < NCAP) {
                    ck[p] = ((ull)(__float_as_uint(gv) & 0x7fffffffu) << 32) | (ull)(uint32_t)(~idx);
                    cg_l[p] = gv;
                }
            }
        }
    }
    __syncthreads();
    int nns = min(nns_sh, NCAP);
    int nns8 = (nns + 7) & ~7;          // zero-pad so the rank loop runs in groups of 8
    for (int i = nns + tid; i < nns8; i += 1024) ck[i] = 0ull;
    __syncthreads();
    ull myk[2]; int myr[2];
#pragma unroll
    for (int q = 0; q < 2; ++q) { int i = tid + 1024 * q; myk[q] = (i < nns) ? ck[i] : 0ull; myr[q] = 0; }
    for (int j = 0; j < nns8; j += 8) {
        ull t0 = ck[j], t1 = ck[j+1], t2 = ck[j+2], t3 = ck[j+3];
        ull t4 = ck[j+4], t5 = ck[j+5], t6 = ck[j+6], t7 = ck[j+7];
#pragma unroll
        for (int q = 0; q < 2; ++q) {
            myr[q] += ((t0 > myk[q]) ? 1 : 0) + ((t1 > myk[q]) ? 1 : 0)
                    + ((t2 > myk[q]) ? 1 : 0) + ((t3 > myk[q]) ? 1 : 0)
                    + ((t4 > myk[q]) ? 1 : 0) + ((t5 > myk[q]) ? 1 : 0)
                    + ((t6 > myk[q]) ? 1 : 0) + ((t7 > myk[q]) ? 1 : 0);
        }
    }
#pragma unroll
    for (int q = 0; q < 2; ++q) {
        int i = tid + 1024 * q;
        if (i < nns && myr[q] < KTOP) {
            uint32_t idx = ~(uint32_t)myk[q];
            int r = myr[q];
            ns_idx[b * KTOP + r] = idx;
            ns_g[b * KTOP + r] = cg_l[i];
            int c = idx / OHW, rr = idx % OHW, s = rr / OH, t = rr % OH;
            ns_pk[b * KTOP + r] = (uint32_t)((c << 12) | (s << 6) | t);
        }
    }
}

// ---------------- fused attempt: selection + recon + err, all-LDS body ----------------
// grid (NATT, NB) x 1024. Waves 0-3: selection (NS rank = index + countB via batched
// 256-loop; support rank = 8-step binsearch in sorted A + countB). Waves 4-15:
// concurrently zero recon + stage W (32KB) into LDS. Scatter/err are LDS-only.
__global__ __launch_bounds__(1024) void k_att2(
    const float* __restrict__ Y, const float* __restrict__ W,
    const int* __restrict__ support_cnt, const uint32_t* __restrict__ support_idx,
    const float* __restrict__ support_val,
    const float* __restrict__ sup_g, const uint32_t* __restrict__ sup_pk,
    const uint32_t* __restrict__ ns_idx, const float* __restrict__ ns_g,
    const uint32_t* __restrict__ ns_pk,
    uint32_t* __restrict__ sel_idx, float* __restrict__ sel_val, double* __restrict__ err)
{
    int a = blockIdx.x, b = blockIdx.y, tid = threadIdx.x;
    int lane = tid & 63, wid = tid >> 6;
    float alpha = ldexpf(1.f, -a);
    int n = support_cnt[b];

    __shared__ float Wlds[NCH * 64];       // 32 KB
    __shared__ float recon[64 * RSTRIDE];  // 18 KB
    __shared__ ull kA[KTOP];               // NS keys, descending (rank-sorted input)
    __shared__ ull kB[KTOP];               // support keys (+dummies)
    __shared__ float s_v[KTOP];
    __shared__ uint32_t s_pk2[KTOP];
    __shared__ double redd[16];

    uint32_t nsi = 0, pk_ns = 0, spi = 0, pk_sup = 0;
    float v_ns = 0.f, v_sup = 0.f;
    ull k_ns = 0, k_sup = 0;
    if (wid < 4) {          // phase 0 (sel waves): load pool, publish keys
        nsi = ns_idx[b * KTOP + tid];
        v_ns = alpha * ns_g[b * KTOP + tid];
        pk_ns = ns_pk[b * KTOP + tid];
        k_ns = ((ull)(__float_as_uint(v_ns) & 0x7fffffffu) << 32) | (ull)(uint32_t)(~nsi);
        kA[tid] = k_ns;
        if (tid < n) {
            spi = support_idx[b * KTOP + tid];
            v_sup = fmaf(alpha, sup_g[b * KTOP + tid], support_val[b * KTOP + tid]);
            pk_sup = sup_pk[b * KTOP + tid];
        } else {
            spi = (uint32_t)(CHW + tid);   // dummy: unique idx, |v|=0 -> never selected
            v_sup = 0.f; pk_sup = 0u;
        }
        k_sup = ((ull)(__float_as_uint(v_sup) & 0x7fffffffu) << 32) | (ull)(uint32_t)(~spi);
        kB[tid] = k_sup;
    }
    __syncthreads();   // barrier 1: keys visible; stagers start now (overlap w/ ranking)

    if (wid < 4) {      // phase 1a: ranking
        int cb_ns = 0, cb_sup = 0;
        for (int j = 0; j < KTOP; j += 8) {
            ull t0 = kB[j], t1 = kB[j+1], t2 = kB[j+2], t3 = kB[j+3];
            ull t4 = kB[j+4], t5 = kB[j+5], t6 = kB[j+6], t7 = kB[j+7];
            cb_ns  += ((t0 > k_ns) ? 1 : 0) + ((t1 > k_ns) ? 1 : 0)
                    + ((t2 > k_ns) ? 1 : 0) + ((t3 > k_ns) ? 1 : 0)
                    + ((t4 > k_ns) ? 1 : 0) + ((t5 > k_ns) ? 1 : 0)
                    + ((t6 > k_ns) ? 1 : 0) + ((t7 > k_ns) ? 1 : 0);
            cb_sup += ((t0 > k_sup) ? 1 : 0) + ((t1 > k_sup) ? 1 : 0)
                    + ((t2 > k_sup) ? 1 : 0) + ((t3 > k_sup) ? 1 : 0)
                    + ((t4 > k_sup) ? 1 : 0) + ((t5 > k_sup) ? 1 : 0)
                    + ((t6 > k_sup) ? 1 : 0) + ((t7 > k_sup) ? 1 : 0);
        }
        int rank_ns = tid + cb_ns;                 // kA sorted desc, unique keys
        int lo = 0, hi = KTOP;                     // count of kA > k_sup (binsearch, desc)
        while (lo < hi) { int mid = (lo + hi) >> 1; if (kA[mid] > k_sup) lo = mid + 1; else hi = mid; }
        int rank_sup = lo + cb_sup;
        size_t o = ((size_t)a * NB + b) * KTOP;
        if (rank_ns < KTOP) {
            s_v[rank_ns] = v_ns; s_pk2[rank_ns] = pk_ns;
            sel_idx[o + rank_ns] = nsi; sel_val[o + rank_ns] = v_ns;
        }
        if (rank_sup < KTOP) {
            s_v[rank_sup] = v_sup; s_pk2[rank_sup] = pk_sup;
            sel_idx[o + rank_sup] = spi; sel_val[o + rank_sup] = v_sup;
        }
    } else {            // phase 1b: stagers zero recon + load W into LDS
        for (int i = tid - 256; i < 64 * RSTRIDE; i += 768) recon[i] = 0.f;
        for (int i = tid - 256; i < (NCH * 64) / 4; i += 768)
            ((float4*)Wlds)[i] = ((const float4*)W)[i];
    }
    __syncthreads();   // barrier 2: selection + staging complete

    // scatter (all-LDS): per wave one candidate, 64 taps across lanes
    for (int task = tid; task < KTOP * 64; task += 1024) {
        int i = task >> 6, tap = task & 63, p = tap >> 3, q = tap & 7;
        uint32_t pk = s_pk2[i];
        float val = s_v[i];
        int c = pk >> 12, s = (pk >> 6) & 63, t = pk & 63;
        atomicAdd(&recon[(s + p) * RSTRIDE + (t + q)], val * Wlds[c * 64 + tap]);
    }
    __syncthreads();   // barrier 3

    float4 y4 = ((const float4*)(Y + b * IMG2))[tid];
    int row = tid >> 4, col = (tid & 15) * 4;
    const float* rr = &recon[row * RSTRIDE + col];
    double accd = 0.0;
    float d0 = y4.x - rr[0]; accd += (double)d0 * (double)d0;
    float d1 = y4.y - rr[1]; accd += (double)d1 * (double)d1;
    float d2 = y4.z - rr[2]; accd += (double)d2 * (double)d2;
    float d3 = y4.w - rr[3]; accd += (double)d3 * (double)d3;
    for (int d = 32; d > 0; d >>= 1) accd += __shfl_xor(accd, d, 64);
    if (lane == 0) redd[wid] = accd;
    __syncthreads();   // barrier 4
    if (tid == 0) {
        double e = 0.0;
#pragma unroll
        for (int w2 = 0; w2 < 16; ++w2) e += redd[w2];
        err[a * NB + b] = e;
    }
}

// ---------------- adopt selected attempt as new X (fused alpha-select + rank sort) ----------------
__global__ __launch_bounds__(256) void k_update(
    const double* __restrict__ l2part, const double* __restrict__ err,
    const uint32_t* __restrict__ sel_idx, const float* __restrict__ sel_val,
    int* __restrict__ support_cnt, uint32_t* __restrict__ support_idx, float* __restrict__ support_val)
{
    int b = blockIdx.x, tid = threadIdx.x;
    __shared__ double esum[NATT + 1];
    __shared__ int sel_sh;
    if (tid < NATT) {
        double e = 0.0;
        for (int b2 = 0; b2 < NB; ++b2) e += err[tid * NB + b2];
        esum[tid] = e;
    } else if (tid == NATT) {
        double l2 = 0.0;
        for (int b2 = 0; b2 < NB; ++b2) l2 += l2part[b2];
        esum[NATT] = l2;
    }
    __syncthreads();
    if (tid == 0) {
        double l2 = esum[NATT];
        int sel = NATT - 1;
        for (int a2 = 0; a2 < NATT; ++a2) if (esum[a2] < l2) { sel = a2; break; }
        sel_sh = sel;
    }
    __syncthreads();
    int a = sel_sh;
    __shared__ uint32_t ki[KTOP];
    __shared__ float kv[KTOP];
    ki[tid] = sel_idx[((size_t)a * NB + b) * KTOP + tid];
    kv[tid] = sel_val[((size_t)a * NB + b) * KTOP + tid];
    __syncthreads();
    uint32_t me = ki[tid];
    int rank = 0;
    for (int j = 0; j < KTOP; j += 8) {
        uint32_t a0 = ki[j], a1 = ki[j+1], a2 = ki[j+2], a3 = ki[j+3];
        uint32_t a4 = ki[j+4], a5 = ki[j+5], a6 = ki[j+6], a7 = ki[j+7];
        rank += ((a0 < me) ? 1 : 0) + ((a1 < me) ? 1 : 0) + ((a2 < me) ? 1 : 0) + ((a3 < me) ? 1 : 0)
              + ((a4 < me) ? 1 : 0) + ((a5 < me) ? 1 : 0) + ((a6 < me) ? 1 : 0) + ((a7 < me) ? 1 : 0);
    }
    support_idx[b * KTOP + rank] = me;
    support_val[b * KTOP + rank] = kv[tid];
    if (tid == 0) support_cnt[b] = KTOP;
}

// ---------------- final output: zero + scatter ----------------
__global__ void k_outzero(float4* __restrict__ out) {
    int i = blockIdx.x * 256 + threadIdx.x;
    if (i < (NB * CHW) / 4) out[i] = make_float4(0.f, 0.f, 0.f, 0.f);
}

__global__ void k_scatter(const uint32_t* __restrict__ support_idx, const float* __restrict__ support_val,
                          float* __restrict__ out) {
    int b = blockIdx.x, tid = threadIdx.x;
    if (tid < KTOP) out[(size_t)b * CHW + support_idx[b * KTOP + tid]] = support_val[b * KTOP + tid];
}

// ---------------- host ----------------
static size_t align256(size_t x) { return (x + 255) & ~(size_t)255; }

extern "C" void kernel_launch(void* const* d_in, const int* in_sizes, int n_in,
                              void* d_out, int out_size, void* d_ws, size_t ws_size,
                              hipStream_t stream)
{
    const float* Y = (const float*)d_in[0];   // (32,1,64,64)
    const float* W = (const float*)d_in[1];   // (128,1,8,8), normalized
    float* out = (float*)d_out;               // (32,128,57,57) — doubles as dense g

    char* p = (char*)d_ws;
    size_t off = 0;
    auto carve = [&](size_t bytes) { void* r = p + off; off = align256(off + bytes); return r; };
    float*    Rg          = (float*)   carve(NB * IMG2 * sizeof(float));
    uint32_t* hist        = (uint32_t*)carve((size_t)NB * NBUCK * sizeof(uint32_t));
    uint32_t* thr         = (uint32_t*)carve(NB * sizeof(uint32_t));
    int*      cand_cnt    = (int*)     carve(NB * NS * sizeof(int));
    double*   l2part      = (double*)  carve(NB * sizeof(double));
    double*   err         = (double*)  carve(NATT * NB * sizeof(double));
    int*      support_cnt = (int*)     carve(NB * sizeof(int));
    uint32_t* support_idx = (uint32_t*)carve(NB * KTOP * sizeof(uint32_t));
    float*    support_val = (float*)   carve(NB * KTOP * sizeof(float));
    uint32_t* sel_idx     = (uint32_t*)carve((size_t)NATT * NB * KTOP * sizeof(uint32_t));
    float*    sel_val     = (float*)   carve((size_t)NATT * NB * KTOP * sizeof(float));
    uint32_t* cand_idx    = (uint32_t*)carve((size_t)NB * NS * SCAP * sizeof(uint32_t));
    float*    cand_g      = (float*)   carve((size_t)NB * NS * SCAP * sizeof(float));
    uint32_t* ns_idx      = (uint32_t*)carve(NB * KTOP * sizeof(uint32_t));
    float*    ns_gbuf     = (float*)   carve(NB * KTOP * sizeof(float));
    uint32_t* ns_pk       = (uint32_t*)carve(NB * KTOP * sizeof(uint32_t));
    float*    sup_gbuf    = (float*)   carve(NB * KTOP * sizeof(float));
    uint32_t* sup_pk      = (uint32_t*)carve(NB * KTOP * sizeof(uint32_t));
    (void)ws_size; (void)in_sizes; (void)n_in; (void)out_size;

    k_init<<<1, 64, 0, stream>>>(support_cnt);
    for (int t = 0; t < 3; ++t) {
        k_resid<<<NB + NZB, 256, 0, stream>>>(Y, W, support_cnt, support_idx, support_val,
                                              Rg, l2part, hist, cand_cnt);
        k_conv<<<dim3(NB, 16), 256, 0, stream>>>(Rg, W, out, hist);
        k_thresh<<<NB, 256, 0, stream>>>(hist, thr);
        k_collect<<<dim3((CHW / 4 + 255) / 256, NB), 256, 0, stream>>>(out, thr, cand_cnt, cand_idx, cand_g);
        k_suppg<<<NB, 1024, 0, stream>>>(out, support_cnt, support_idx,
                                         cand_cnt, cand_idx, cand_g,
                                         ns_idx, ns_gbuf, ns_pk, sup_gbuf, sup_pk);
        k_att2<<<dim3(NATT, NB), 1024, 0, stream>>>(Y, W, support_cnt, support_idx, support_val,
                                                    sup_gbuf, sup_pk, ns_idx, ns_gbuf, ns_pk,
                                                    sel_idx, sel_val, err);
        k_update<<<NB, 256, 0, stream>>>(l2part, err, sel_idx, sel_val,
                                         support_cnt, support_idx, support_val);
    }
    k_outzero<<<((NB * CHW) / 4 + 255) / 256, 256, 0, stream>>>((float4*)out);
    k_scatter<<<NB, 256, 0, stream>>>(support_idx, support_val, out);
}